// Round 6
// baseline (135.301 us; speedup 1.0000x reference)
//
#include <hip/hip_runtime.h>
#include <math.h>

// Problem constants (from reference): B=1, C=16, H=72, W=96, N=6912
#define NPIX 6912
#define IMW  96
#define NJC  64                 // j-chunks in grid.y
#define JLEN (NPIX / NJC)       // 108 j-iterations per thread

// d_ws float-offset layout (~1.16 MB total)
#define OFF_PACK1 0                         // [N][4]: x0,x1,x2,sq1
#define OFF_PACK2 (OFF_PACK1 + NPIX * 4)    // [N][8]: y0,z0,y1,z1, y2,z2,sq2,sq2n (clean/noisy interleaved)
#define OFF_F1N   (OFF_PACK2 + NPIX * 8)    // [N][16] normalized feature1
#define OFF_F2N   (OFF_F1N + NPIX * 16)     // [N][16] normalized feature2

#if __has_builtin(__builtin_amdgcn_exp2f)
#define EXP2F(x) __builtin_amdgcn_exp2f(x)
#else
#define EXP2F(x) exp2f(x)
#endif
#if __has_builtin(__builtin_amdgcn_sqrtf)
#define SQRTF(x) __builtin_amdgcn_sqrtf(x)
#else
#define SQRTF(x) sqrtf(x)
#endif
// -0.1 * log2(e): folds dist_coef and the exp->exp2 conversion into one mul
#define NEG_COEF_LOG2E (-0.14426950408889634f)

typedef float f32x2 __attribute__((ext_vector_type(2)));

__device__ __forceinline__ f32x2 fma2(f32x2 a, f32x2 b, f32x2 c) {
  return __builtin_elementwise_fma(a, b, c);
}
__device__ __forceinline__ f32x2 max2(f32x2 a, f32x2 b) {
  return __builtin_elementwise_max(a, b);
}
__device__ __forceinline__ f32x2 mk2(float x, float y) {
  f32x2 r; r.x = x; r.y = y; return r;
}

__device__ __forceinline__ float blk_reduce256(float v) {
  __shared__ float sm[4];
#pragma unroll
  for (int o = 32; o > 0; o >>= 1) v += __shfl_down(v, o, 64);
  const int lane = threadIdx.x & 63;
  const int wv = threadIdx.x >> 6;
  if (lane == 0) sm[wv] = v;
  __syncthreads();
  return (sm[0] + sm[1]) + (sm[2] + sm[3]);
}

// Per-pixel precompute: xyz1/sq1, pose-transformed xyz2 (clean+noisy
// INTERLEAVED for packed-f32 main loop), L2-normalized features
// (transposed to [N][16]), and the feature-norm sum.
__global__ __launch_bounds__(256) void k_pre(
    const float* __restrict__ f1, const float* __restrict__ f2,
    const float* __restrict__ dep1, const float* __restrict__ dep2,
    const float* __restrict__ pose, const float* __restrict__ noise,
    float* __restrict__ ws, float* __restrict__ out) {
  __shared__ float sPose[24];          // [0..11] = P rows0..2, [12..23] = P@noise rows0..2
  const int t = threadIdx.x;
  if (t < 12) {
    sPose[t] = pose[t];
  } else if (t < 24) {
    const int u = t - 12, r = u >> 2, c = u & 3;
    float s = 0.f;
#pragma unroll
    for (int k = 0; k < 4; ++k) s = fmaf(pose[r * 4 + k], noise[k * 4 + c], s);
    sPose[t] = s;
  }
  __syncthreads();

  const int i = blockIdx.x * 256 + t;
  const int vi = i / IMW;
  const int ui = i - vi * IMW;
  // invK @ (u,v,1): p = (1, u/48 - 1, v/48 - 0.75)
  const float inv48 = (float)(1.0 / 48.0);
  const float p1c = fmaf((float)ui, inv48, -1.0f);
  const float p2c = fmaf((float)vi, inv48, -0.75f);

  const float d1 = dep1[i];
  const float x0 = d1, x1 = d1 * p1c, x2 = d1 * p2c;
  const float sq1 = fmaf(x2, x2, fmaf(x1, x1, x0 * x0));
  *(float4*)(ws + OFF_PACK1 + (size_t)i * 4) = make_float4(x0, x1, x2, sq1);

  const float d2 = dep2[i];
  const float w0 = d2, w1 = d2 * p1c, w2 = d2 * p2c;
  const float* P  = sPose;
  const float* Pn = sPose + 12;
  const float y0 = fmaf(P[0], w0, fmaf(P[1], w1, fmaf(P[2],  w2, P[3])));
  const float y1 = fmaf(P[4], w0, fmaf(P[5], w1, fmaf(P[6],  w2, P[7])));
  const float y2 = fmaf(P[8], w0, fmaf(P[9], w1, fmaf(P[10], w2, P[11])));
  const float sq2 = fmaf(y2, y2, fmaf(y1, y1, y0 * y0));
  const float z0 = fmaf(Pn[0], w0, fmaf(Pn[1], w1, fmaf(Pn[2],  w2, Pn[3])));
  const float z1 = fmaf(Pn[4], w0, fmaf(Pn[5], w1, fmaf(Pn[6],  w2, Pn[7])));
  const float z2 = fmaf(Pn[8], w0, fmaf(Pn[9], w1, fmaf(Pn[10], w2, Pn[11])));
  const float sq2n = fmaf(z2, z2, fmaf(z1, z1, z0 * z0));
  // clean/noisy interleaved: (y0,z0,y1,z1) and (y2,z2,sq2,sq2n)
  *(float4*)(ws + OFF_PACK2 + (size_t)i * 8)     = make_float4(y0, z0, y1, z1);
  *(float4*)(ws + OFF_PACK2 + (size_t)i * 8 + 4) = make_float4(y2, z2, sq2, sq2n);

  float a[16], b[16];
  float sa = 0.f, sb = 0.f;
#pragma unroll
  for (int c = 0; c < 16; ++c) {
    a[c] = f1[c * NPIX + i]; sa = fmaf(a[c], a[c], sa);
    b[c] = f2[c * NPIX + i]; sb = fmaf(b[c], b[c], sb);
  }
  const float na = sqrtf(sa), nb = sqrtf(sb);
#pragma unroll
  for (int c = 0; c < 16; ++c) { a[c] = a[c] / na; b[c] = b[c] / nb; }
#pragma unroll
  for (int c = 0; c < 16; c += 4) {
    *(float4*)(ws + OFF_F1N + (size_t)i * 16 + c) = make_float4(a[c], a[c+1], a[c+2], a[c+3]);
    *(float4*)(ws + OFF_F2N + (size_t)i * 16 + c) = make_float4(b[c], b[c+1], b[c+2], b[c+3]);
  }
  const float part = blk_reduce256(na + nb);
  if (t == 0) atomicAdd(out + 2, 100.0f * part);
}

// Main N x N reduction, packed-f32 (v_pk_fma_f32) version.
// Thread owns row i; block stages its j-chunk (10.4 KB) into LDS once
// (wave-uniform reads = free broadcast). Per pair: 8 packed-FMA gram dot +
// one packed clean/noisy distance chain + 4 transcendentals.
__global__ __launch_bounds__(256) void k_main(const float* __restrict__ ws,
                                              float* __restrict__ out) {
  __shared__ float4 sF[JLEN * 4];   // normalized feature2 chunk
  __shared__ float4 sP[JLEN * 2];   // pack2 chunk (interleaved clean/noisy)

  const int j0 = blockIdx.y * JLEN;
  const float4* gF = (const float4*)(ws + OFF_F2N)   + (size_t)j0 * 4;
  const float4* gP = (const float4*)(ws + OFF_PACK2) + (size_t)j0 * 2;
  for (int tt = threadIdx.x; tt < JLEN * 4; tt += 256) sF[tt] = gF[tt];
  for (int tt = threadIdx.x; tt < JLEN * 2; tt += 256) sP[tt] = gP[tt];

  const int i = blockIdx.x * 256 + threadIdx.x;
  const float4 pk = *(const float4*)(ws + OFF_PACK1 + (size_t)i * 4);
  const f32x2 x0v = mk2(pk.x, pk.x), x1v = mk2(pk.y, pk.y), x2v = mk2(pk.z, pk.z);
  const f32x2 sq1v = mk2(pk.w, pk.w);
  const f32x2 m2v = mk2(-2.f, -2.f);
  const f32x2 zerov = mk2(0.f, 0.f);
  f32x2 f1p[8];
#pragma unroll
  for (int c = 0; c < 4; ++c) {
    const float4 tq = *(const float4*)(ws + OFF_F1N + (size_t)i * 16 + c * 4);
    f1p[c * 2 + 0] = mk2(tq.x, tq.y);
    f1p[c * 2 + 1] = mk2(tq.z, tq.w);
  }
  __syncthreads();

  // accv.x accumulates sum(k1*g), accv.y accumulates sum(k2*g);
  // the (k1-k2) subtraction happens once at the end.
  f32x2 accv = zerov;
#pragma unroll 2
  for (int jj = 0; jj < JLEN; ++jj) {
    const float4 fa = sF[jj * 4 + 0];
    const float4 fb = sF[jj * 4 + 1];
    const float4 fc = sF[jj * 4 + 2];
    const float4 fd = sF[jj * 4 + 3];
    const float4 Q0 = sP[jj * 2 + 0];   // y0,z0,y1,z1
    const float4 Q1 = sP[jj * 2 + 1];   // y2,z2,sq2,sq2n

    // gram dot: 8 packed FMAs in two chains + packed add + horizontal add
    f32x2 gA = f1p[0] * mk2(fa.x, fa.y);
    gA = fma2(f1p[1], mk2(fa.z, fa.w), gA);
    gA = fma2(f1p[2], mk2(fb.x, fb.y), gA);
    gA = fma2(f1p[3], mk2(fb.z, fb.w), gA);
    f32x2 gB = f1p[4] * mk2(fc.x, fc.y);
    gB = fma2(f1p[5], mk2(fc.z, fc.w), gB);
    gB = fma2(f1p[6], mk2(fd.x, fd.y), gB);
    gB = fma2(f1p[7], mk2(fd.z, fd.w), gB);
    const f32x2 gv2 = gA + gB;
    const float g = gv2.x + gv2.y;

    // packed clean/noisy distance kernel
    const f32x2 yz0 = mk2(Q0.x, Q0.y), yz1 = mk2(Q0.z, Q0.w);
    const f32x2 yz2 = mk2(Q1.x, Q1.y), s2  = mk2(Q1.z, Q1.w);
    f32x2 dt2 = x0v * yz0;
    dt2 = fma2(x1v, yz1, dt2);
    dt2 = fma2(x2v, yz2, dt2);
    f32x2 d2v = fma2(m2v, dt2, sq1v + s2);
    d2v = max2(d2v, zerov);
    f32x2 rt;
    rt.x = SQRTF(d2v.x);
    rt.y = SQRTF(d2v.y);
    f32x2 kv;
    kv.x = EXP2F(NEG_COEF_LOG2E * rt.x);
    kv.y = EXP2F(NEG_COEF_LOG2E * rt.y);
    accv = fma2(kv, mk2(g, g), accv);
  }
  const float part = blk_reduce256(accv.x - accv.y);
  if (threadIdx.x == 0) {
    atomicAdd(out + 0, -part);   // final_loss
    atomicAdd(out + 1, -part);   // inner_neg
  }
}

extern "C" void kernel_launch(void* const* d_in, const int* in_sizes, int n_in,
                              void* d_out, int out_size, void* d_ws, size_t ws_size,
                              hipStream_t stream) {
  const float* f1    = (const float*)d_in[0];
  const float* f2    = (const float*)d_in[1];
  const float* dep1  = (const float*)d_in[2];
  const float* dep2  = (const float*)d_in[3];
  const float* pose  = (const float*)d_in[4];
  const float* noise = (const float*)d_in[5];
  float* out = (float*)d_out;
  float* ws  = (float*)d_ws;

  (void)hipMemsetAsync(out, 0, (size_t)out_size * sizeof(float), stream);
  k_pre<<<NPIX / 256, 256, 0, stream>>>(f1, f2, dep1, dep2, pose, noise, ws, out);
  k_main<<<dim3(NPIX / 256, NJC), 256, 0, stream>>>(ws, out);
}